// Round 9
// baseline (540.633 us; speedup 1.0000x reference)
//
#include <hip/hip_runtime.h>
#include <stdint.h>

#define Hh    51
#define Bsz   1024
#define Tin   512
#define Ttot  576      // Tin + future(64)
#define NBB   8        // batches per block (grid 128)
#define BROWS 8        // LDS batch rows (mirror trick: cols 8-15 read row nn&7)
#define NW    7        // waves per block; each wave owns 2 M-tiles (14 >= 13)
#define BLK   (NW*64)  // 448
#define BST   136      // per-batch k-stride (uint16) = 68 dwords
#define WS    18       // wsum per-wave stride (16 partials + 2 pad)

#define L2E   1.4426950408889634f    // log2(e)
#define TL2E  2.8853900817779268f    // 2*log2(e)

typedef __attribute__((ext_vector_type(8))) _Float16 half8;  // 8 x f16 frag
typedef __attribute__((ext_vector_type(4))) float f32x4;     // C/D frag

__device__ __forceinline__ float rcpf(float x){ return __builtin_amdgcn_rcpf(x); }
__device__ __forceinline__ float exp2f_fast(float x){
#if __has_builtin(__builtin_amdgcn_exp2f)
    return __builtin_amdgcn_exp2f(x);
#else
    return exp2f(x);
#endif
}

// Fused LSTM pointwise, rcp-merged: 7 trans ops.
// Inputs pre-scaled: vi,vf,vo by log2e; vg by 2log2e. Updates c, returns h.
__device__ __forceinline__ float cell_fuse(float vi, float vf, float vg,
                                           float vo, float& c){
    float Ei = exp2f_fast(-vi), Ef = exp2f_fast(-vf), Eg = exp2f_fast(-vg);
    float A = 1.f + Ef, B = 1.f + Ei, C = 1.f + Eg, D = 1.f - Eg;
    float BC = B*C;
    float R  = rcpf(A*BC);
    float cn = __builtin_fmaf(c, BC*R, (A*D)*R);
    c = cn;
    float Ec = exp2f_fast(fminf(-cn*TL2E, 120.f));
    float Eo = exp2f_fast(-vo);
    float R2 = rcpf((1.f+Eo)*(1.f+Ec));
    return (1.f - Ec) * R2;
}

__device__ __forceinline__ uint16_t f2h(float f){
    union{ _Float16 h; uint16_t u; } v; v.h = (_Float16)f;   // v_cvt_f16_f32 RNE
    return v.u;
}

// quad reduction (sum over lanes ^16 and ^32), R4/R6-proven shfl_xor chain.
__device__ __forceinline__ float qsum(float x){
    x += __shfl_xor(x, 16, 64);
    x += __shfl_xor(x, 32, 64);
    return x;
}
#define MFMA __builtin_amdgcn_mfma_f32_16x16x32_f16

// R23: deferred qsum. R8 showed the store-drain was not the stall; the two
// CHAINED shfl_xor (DS pipe, ~120 cy each) sat after the cell chain and
// before the barrier on EVERY step. Fix: carry part(t)=Wl*h2(t) in a
// register; at body START of step t+1 qsum it and write wsum[t&1] -- the
// shfl latency now overlaps MFMA/cell work. Out-writer lag 1->2 (reads
// wsum[cur] for out(t-2), ring entry (t-2)&7, flush at t==1 mod 8). Outputs
// bit-identical (same reduction tree, later store). Future loop keeps the
// R6 lag-1 schedule; epilogue between loops reduces the carried part,
// emits out(504..509), and re-establishes parity (future t=511 reads
// wsum[0] which the epilogue writes).
__global__ __launch_bounds__(BLK, 2)
void lstm_f16e(const float* __restrict__ inp,    // [B, Tin]
               const float* __restrict__ Wih1,   // [204, 1]
               const float* __restrict__ Whh1,   // [204, 51]
               const float* __restrict__ bih1,   // [204]
               const float* __restrict__ bhh1,   // [204]
               const float* __restrict__ Wih2,   // [204, 51]
               const float* __restrict__ Whh2,   // [204, 51]
               const float* __restrict__ bih2,   // [204]
               const float* __restrict__ bhh2,   // [204]
               const float* __restrict__ Wl,     // [1, 51]
               const float* __restrict__ blp,    // [1]
               float* __restrict__ outp)         // [B, Ttot]
{
    const int tid = threadIdx.x;
    const int wv  = tid >> 6, ln = tid & 63;
    const int quad = ln >> 4, nn = ln & 15;
    const bool lo = (nn < 8);
    const int ba  = nn & 7;            // batch owned/read by this lane
    const int b0  = blockIdx.x * NBB;

    __shared__ __align__(16) uint16_t Bh[2][BROWS*BST];
    __shared__ float wsum[2][NW*WS];      // parity-dbuf output partials
    __shared__ float oring[8][NBB];       // wave-6-private output ring

    for (int k = tid; k < BROWS*BST; k += BLK) { Bh[0][k] = 0; Bh[1][k] = 0; }
    if (tid < NW*WS) { wsum[0][tid] = 0.f; wsum[1][tid] = 0.f; }

    // ---- A fragments for 2 tiles; weights pre-scaled by log2e (2log2e for
    // g rows), single f16 product. Wave 6 tile 1 = all-zero dummy. ----
    half8 a1[2][2], a2[2][4];
    f32x4 bias1[2], bias2[2], wih1v[2];
    float wlu[2];
#pragma unroll
    for (int tl = 0; tl < 2; ++tl) {
        const bool tv = (wv + 7*tl) < 13;
        const int lr = 16*(wv + 7*tl) + nn;
        const int ua_ = lr >> 2, ga = lr & 3;
        const bool av = tv && (ua_ < Hh);
        const int pr = av ? (ga*Hh + ua_) : 0;
        const float rs = (ga == 2) ? TL2E : L2E;
#pragma unroll
        for (int s = 0; s < 2; ++s)
#pragma unroll
            for (int j = 0; j < 8; ++j) {
                int k = 32*s + quad*8 + j;
                float w = (av && k < Hh) ? Whh1[pr*Hh + k]*rs : 0.f;
                a1[tl][s][j] = (_Float16)w;
            }
#pragma unroll
        for (int s = 0; s < 4; ++s)
#pragma unroll
            for (int j = 0; j < 8; ++j) {
                int k = 32*s + quad*8 + j;
                float w = 0.f;
                if (av) {
                    if (k < Hh)                    w = Wih2[pr*Hh + k]*rs;
                    else if (k >= 64 && k < 64+Hh) w = Whh2[pr*Hh + (k-64)]*rs;
                }
                a2[tl][s][j] = (_Float16)w;
            }
        const int u = 4*(wv + 7*tl) + quad;
        const bool uv = tv && (u < Hh);
#pragma unroll
        for (int i = 0; i < 4; ++i) {
            int pri = uv ? (i*Hh + u) : 0;
            float gs = (i == 2) ? TL2E : L2E;
            bias1[tl][i] = uv ? (bih1[pri] + bhh1[pri])*gs : 0.f;
            bias2[tl][i] = uv ? (bih2[pri] + bhh2[pri])*gs : 0.f;
            wih1v[tl][i] = uv ? Wih1[pri]*gs : 0.f;
        }
        wlu[tl] = uv ? Wl[u] : 0.f;
    }
    const float blv = blp[0];

    // ---- assigned cell for this lane: (ua, ba); c-state lives here ----
    const int  ua  = 4*(wv + (lo ? 0 : 7)) + quad;
    const bool uva = (ua < Hh);
    const float wlua = lo ? wlu[0] : wlu[1];
    float c1 = 0.f, c2 = 0.f;

    // ---- prologue: h1(0) for assigned cell (pure per-lane math) ----
    {
        float b1a[4], w1a[4];
#pragma unroll
        for (int i = 0; i < 4; ++i) {
            b1a[i] = lo ? bias1[0][i] : bias1[1][i];
            w1a[i] = lo ? wih1v[0][i] : wih1v[1][i];
        }
        float x0 = inp[(size_t)(b0 + ba)*Tin];
        float vi = __builtin_fmaf(w1a[0], x0, b1a[0]);
        float vf = __builtin_fmaf(w1a[1], x0, b1a[1]);
        float vg = __builtin_fmaf(w1a[2], x0, b1a[2]);
        float vo = __builtin_fmaf(w1a[3], x0, b1a[3]);
        float h1n = cell_fuse(vi, vf, vg, vo, c1);
        if (uva) Bh[0][ba*BST + ua] = f2h(h1n);
    }
    float xreg = (Tin > 1) ? inp[(size_t)(b0 + ba)*Tin + 1] : 0.f;  // x(1), all lanes
    float part_reg = 0.f;   // carried Wl*h2 partial (reduced one step later)
    __syncthreads();

    // ================= input-mode loop: t in [0, Tin-1) =================
    for (int t = 0; t < Tin-1; ++t) {
        const int cur = t & 1, nxt = cur ^ 1;

        // ---- B-frag reads first (start LDS latency early); mirror rows ----
        const uint16_t* rb = &Bh[cur][ba*BST + quad*8];
        half8 s0 = *(const half8*)(rb),      s1 = *(const half8*)(rb + 32);
        half8 s2 = *(const half8*)(rb + 64), s3 = *(const half8*)(rb + 96);

        // ---- deferred reduction of part(t-1): shfl latency overlaps the
        // MFMA/cell work below instead of sitting before the barrier ----
        {
            float red = qsum(part_reg);
            if (ln < 16) wsum[nxt][wv*WS + ln] = red;   // nxt == (t-1)&1
        }

        // ---- out(t-2): reader (wave 6) from wsum[cur]; ring + 8-batch flush ----
        if (wv == NW-1 && t >= 2) {
            float osum = blv;
#pragma unroll
            for (int w = 0; w < NW; ++w)
                osum += wsum[cur][w*WS + ba] + wsum[cur][w*WS + 8 + ba];
            if (ln < NBB) oring[(t-2) & 7][ln] = osum;
            if ((t & 7) == 1 && t >= 9 && ln < NBB) {  // ring idx 7 just filled
                float4 o0 = { oring[0][ln], oring[1][ln],
                              oring[2][ln], oring[3][ln] };
                float4 o1 = { oring[4][ln], oring[5][ln],
                              oring[6][ln], oring[7][ln] };
                float* op = &outp[(size_t)(b0 + ln)*Ttot + (t - 9)];
                *(float4*)(op)     = o0;
                *(float4*)(op + 4) = o1;
            }
        }
        float xn = (t + 2 < Tin) ? inp[(size_t)(b0 + ba)*Tin + t + 2] : 0.f;

        // ---- flat MFMA issue: L2(t) both tiles + L1(t+1) both tiles ----
        f32x4 aA0 = bias2[0], aB0 = {0.f,0.f,0.f,0.f};
        f32x4 aA1 = bias2[1], aB1 = {0.f,0.f,0.f,0.f};
        f32x4 bA0, bA1, bB0 = {0.f,0.f,0.f,0.f}, bB1 = {0.f,0.f,0.f,0.f};
#pragma unroll
        for (int i = 0; i < 4; ++i) {
            bA0[i] = __builtin_fmaf(wih1v[0][i], xreg, bias1[0][i]);
            bA1[i] = __builtin_fmaf(wih1v[1][i], xreg, bias1[1][i]);
        }
        aA0 = MFMA(a2[0][0], s0, aA0, 0,0,0);  aB0 = MFMA(a2[0][1], s1, aB0, 0,0,0);
        aA1 = MFMA(a2[1][0], s0, aA1, 0,0,0);  aB1 = MFMA(a2[1][1], s1, aB1, 0,0,0);
        bA0 = MFMA(a1[0][0], s0, bA0, 0,0,0);  bB0 = MFMA(a1[0][1], s1, bB0, 0,0,0);
        bA1 = MFMA(a1[1][0], s0, bA1, 0,0,0);  bB1 = MFMA(a1[1][1], s1, bB1, 0,0,0);
        aA0 = MFMA(a2[0][2], s2, aA0, 0,0,0);  aB0 = MFMA(a2[0][3], s3, aB0, 0,0,0);
        aA1 = MFMA(a2[1][2], s2, aA1, 0,0,0);  aB1 = MFMA(a2[1][3], s3, aB1, 0,0,0);

        // ---- select own tile's gates (no shuffle needed) ----
        f32x4 g2t0 = aA0 + aB0, g2t1 = aA1 + aB1;
        f32x4 g1t0 = bA0 + bB0, g1t1 = bA1 + bB1;
        float g2[4], g1[4];
#pragma unroll
        for (int i = 0; i < 4; ++i) {
            g2[i] = lo ? g2t0[i] : g2t1[i];
            g1[i] = lo ? g1t0[i] : g1t1[i];
        }

        // ---- 2 independent cell chains per lane; stores issue ASAP ----
        float h2v = cell_fuse(g2[0], g2[1], g2[2], g2[3], c2);
        float h1v = cell_fuse(g1[0], g1[1], g1[2], g1[3], c1);
        if (uva) {
            Bh[nxt][ba*BST + 64 + ua] = f2h(h2v);
            Bh[nxt][ba*BST      + ua] = f2h(h1v);
        }
        part_reg = wlua * h2v;      // reduced at body start of step t+1

        __syncthreads();
        xreg = xn;
    }

    // ---- epilogue between loops ----
    // part_reg = part(510); wsum[1] holds reduced part(509) (written at
    // t=510, visible after its barrier). Ring entries 0..4 = out(504..508).
    {
        float red = qsum(part_reg);
        if (ln < 16) wsum[0][wv*WS + ln] = red;    // (510)&1 == 0
    }
    if (wv == NW-1 && ln < NBB) {
#pragma unroll
        for (int k = 0; k < 5; ++k)
            outp[(size_t)(b0 + ln)*Ttot + 504 + k] = oring[k][ln];
        float osum = blv;
#pragma unroll
        for (int w = 0; w < NW; ++w)
            osum += wsum[1][w*WS + ba] + wsum[1][w*WS + 8 + ba];
        outp[(size_t)(b0 + ln)*Ttot + 509] = osum;
    }
    __syncthreads();

    // ================= future loop: t in [Tin-1, Ttot) =================
    // R6 lag-1 schedule: writer->wsum[cur] in-step, reader->wsum[nxt].
    // At t=511 reader uses wsum[nxt=0] = epilogue's reduced part(510). ✓
    for (int t = Tin-1; t < Ttot; ++t) {
        const int cur = t & 1, nxt = cur ^ 1;

        const uint16_t* rb = &Bh[cur][ba*BST + quad*8];
        half8 s0 = *(const half8*)(rb),      s1 = *(const half8*)(rb + 32);
        half8 s2 = *(const half8*)(rb + 64), s3 = *(const half8*)(rb + 96);

        if (wv == NW-1) {       // t >= 511 > 0 always
            float osum = blv;
#pragma unroll
            for (int w = 0; w < NW; ++w)
                osum += wsum[nxt][w*WS + ba] + wsum[nxt][w*WS + 8 + ba];
            if (ln < NBB) outp[(size_t)(b0 + ln)*Ttot + (t-1)] = osum;
        }

        // ---- L2(t), both tiles flat ----
        f32x4 aA0 = bias2[0], aB0 = {0.f,0.f,0.f,0.f};
        f32x4 aA1 = bias2[1], aB1 = {0.f,0.f,0.f,0.f};
        aA0 = MFMA(a2[0][0], s0, aA0, 0,0,0);  aB0 = MFMA(a2[0][1], s1, aB0, 0,0,0);
        aA1 = MFMA(a2[1][0], s0, aA1, 0,0,0);  aB1 = MFMA(a2[1][1], s1, aB1, 0,0,0);
        aA0 = MFMA(a2[0][2], s2, aA0, 0,0,0);  aB0 = MFMA(a2[0][3], s3, aB0, 0,0,0);
        aA1 = MFMA(a2[1][2], s2, aA1, 0,0,0);  aB1 = MFMA(a2[1][3], s3, aB1, 0,0,0);
        f32x4 g2t0 = aA0 + aB0, g2t1 = aA1 + aB1;
        float g2[4];
#pragma unroll
        for (int i = 0; i < 4; ++i) g2[i] = lo ? g2t0[i] : g2t1[i];
        float h2v = cell_fuse(g2[0], g2[1], g2[2], g2[3], c2);
        if (uva) Bh[nxt][ba*BST + 64 + ua] = f2h(h2v);
        float part = qsum(wlua * h2v);
        if (ln < 16) wsum[cur][wv*WS + ln] = part;
        __syncthreads();                                   // bar 1

        // ---- x(t+1) = out(t), then L1(t+1), both tiles flat ----
        if (t + 1 < Ttot) {
            float osum = blv;
#pragma unroll
            for (int w = 0; w < NW; ++w)
                osum += wsum[cur][w*WS + ba] + wsum[cur][w*WS + 8 + ba];
            f32x4 bA0, bA1, bB0 = {0.f,0.f,0.f,0.f}, bB1 = {0.f,0.f,0.f,0.f};
#pragma unroll
            for (int i = 0; i < 4; ++i) {
                bA0[i] = __builtin_fmaf(wih1v[0][i], osum, bias1[0][i]);
                bA1[i] = __builtin_fmaf(wih1v[1][i], osum, bias1[1][i]);
            }
            bA0 = MFMA(a1[0][0], s0, bA0, 0,0,0);  bB0 = MFMA(a1[0][1], s1, bB0, 0,0,0);
            bA1 = MFMA(a1[1][0], s0, bA1, 0,0,0);  bB1 = MFMA(a1[1][1], s1, bB1, 0,0,0);
            f32x4 g1t0 = bA0 + bB0, g1t1 = bA1 + bB1;
            float g1[4];
#pragma unroll
            for (int i = 0; i < 4; ++i) g1[i] = lo ? g1t0[i] : g1t1[i];
            float h1v = cell_fuse(g1[0], g1[1], g1[2], g1[3], c1);
            if (uva) Bh[nxt][ba*BST + ua] = f2h(h1v);
            __syncthreads();                               // bar 2 (future only)
        }
    }

    // final output (t = Ttot-1): wsum[(Ttot-1)&1] visible after last barrier
    if (wv == NW-1) {
        float osum = blv;
#pragma unroll
        for (int w = 0; w < NW; ++w)
            osum += wsum[(Ttot-1)&1][w*WS + ba] + wsum[(Ttot-1)&1][w*WS + 8 + ba];
        if (ln < NBB) outp[(size_t)(b0 + ln)*Ttot + (Ttot-1)] = osum;
    }
}

extern "C" void kernel_launch(void* const* d_in, const int* in_sizes, int n_in,
                              void* d_out, int out_size, void* d_ws, size_t ws_size,
                              hipStream_t stream) {
    (void)in_sizes; (void)n_in; (void)out_size; (void)d_ws; (void)ws_size;
    lstm_f16e<<<dim3(Bsz / NBB), dim3(BLK), 0, stream>>>(
        (const float*)d_in[0], (const float*)d_in[1],
        (const float*)d_in[2], (const float*)d_in[3],
        (const float*)d_in[4], (const float*)d_in[5],
        (const float*)d_in[6], (const float*)d_in[7],
        (const float*)d_in[8], (const float*)d_in[9],
        (const float*)d_in[10], (float*)d_out);
}

// Round 10
// 496.378 us; speedup vs baseline: 1.0892x; 1.0892x over previous
//
#include <hip/hip_runtime.h>
#include <stdint.h>

#define Hh    51
#define Bsz   1024
#define Tin   512
#define Ttot  576      // Tin + future(64)
#define NBB   8        // batches per block (grid 128)
#define BROWS 8        // LDS batch rows (mirror trick: cols 8-15 read row nn&7)
#define NTP   7        // tile-pairs (13 M-tiles in 7 pairs)
#define NWV   14       // 7 L2 waves + 7 L1 waves (layer-split specialization)
#define BLK   (NWV*64) // 896
#define BST   136      // per-batch k-stride (uint16) = 68 dwords
#define WS    18       // wsum per-wave stride (16 partials + 2 pad)

#define L2E   1.4426950408889634f    // log2(e)
#define TL2E  2.8853900817779268f    // 2*log2(e)

typedef __attribute__((ext_vector_type(8))) _Float16 half8;  // 8 x f16 frag
typedef __attribute__((ext_vector_type(4))) float f32x4;     // C/D frag

__device__ __forceinline__ float rcpf(float x){ return __builtin_amdgcn_rcpf(x); }
__device__ __forceinline__ float exp2f_fast(float x){
#if __has_builtin(__builtin_amdgcn_exp2f)
    return __builtin_amdgcn_exp2f(x);
#else
    return exp2f(x);
#endif
}

// Fused LSTM pointwise, rcp-merged: 7 trans ops.
// Inputs pre-scaled: vi,vf,vo by log2e; vg by 2log2e. Updates c, returns h.
__device__ __forceinline__ float cell_fuse(float vi, float vf, float vg,
                                           float vo, float& c){
    float Ei = exp2f_fast(-vi), Ef = exp2f_fast(-vf), Eg = exp2f_fast(-vg);
    float A = 1.f + Ef, B = 1.f + Ei, C = 1.f + Eg, D = 1.f - Eg;
    float BC = B*C;
    float R  = rcpf(A*BC);
    float cn = __builtin_fmaf(c, BC*R, (A*D)*R);
    c = cn;
    float Ec = exp2f_fast(fminf(-cn*TL2E, 120.f));
    float Eo = exp2f_fast(-vo);
    float R2 = rcpf((1.f+Eo)*(1.f+Ec));
    return (1.f - Ec) * R2;
}

__device__ __forceinline__ uint16_t f2h(float f){
    union{ _Float16 h; uint16_t u; } v; v.h = (_Float16)f;   // v_cvt_f16_f32 RNE
    return v.u;
}

// quad reduction (sum over lanes ^16 and ^32), R4/R6-proven shfl_xor chain.
__device__ __forceinline__ float qsum(float x){
    x += __shfl_xor(x, 16, 64);
    x += __shfl_xor(x, 32, 64);
    return x;
}
#define MFMA __builtin_amdgcn_mfma_f32_16x16x32_f16

// R24: layer-split wave specialization. R6/R8's 7-wave form had 1.75 waves/
// SIMD in barrier lockstep; ~75% of step time was dependency bubbles the
// lone co-wave (same phase, same pipes) couldn't hide. Split each step's
// work by ROLE: waves 0-6 = L2(t) only (4 slabs, 8 MFMA, h2 cell, wsum);
// waves 7-13 = L1(t+1) only (2 slabs, 4 MFMA, h1 cell). Same total work,
// half-length chains, 3.5 waves/SIMD. Numerics and LDS protocol identical
// to R6 (lag-1 wsum; R9's deferred qsum reverted -- it regressed). A-frags
// live in one union array af[8] to hold VGPR ~90.
__global__ __launch_bounds__(BLK, 1)
void lstm_f16s2(const float* __restrict__ inp,    // [B, Tin]
                const float* __restrict__ Wih1,   // [204, 1]
                const float* __restrict__ Whh1,   // [204, 51]
                const float* __restrict__ bih1,   // [204]
                const float* __restrict__ bhh1,   // [204]
                const float* __restrict__ Wih2,   // [204, 51]
                const float* __restrict__ Whh2,   // [204, 51]
                const float* __restrict__ bih2,   // [204]
                const float* __restrict__ bhh2,   // [204]
                const float* __restrict__ Wl,     // [1, 51]
                const float* __restrict__ blp,    // [1]
                float* __restrict__ outp)         // [B, Ttot]
{
    const int tid = threadIdx.x;
    const int wv  = tid >> 6, ln = tid & 63;
    const int quad = ln >> 4, nn = ln & 15;
    const bool lo = (nn < 8);
    const int ba  = nn & 7;            // batch owned/read by this lane
    const int b0  = blockIdx.x * NBB;
    const bool isL2 = (wv < NTP);      // role: L2(t) vs L1(t+1)
    const int  wvv  = isL2 ? wv : wv - NTP;

    __shared__ __align__(16) uint16_t Bh[2][BROWS*BST];
    __shared__ float wsum[2][NTP*WS];     // parity-dbuf output partials

    for (int k = tid; k < BROWS*BST; k += BLK) { Bh[0][k] = 0; Bh[1][k] = 0; }
    if (tid < NTP*WS) { wsum[0][tid] = 0.f; wsum[1][tid] = 0.f; }

    // ---- A fragments, role-unioned: L2 uses af[tl*4+s] (s=0..3, Wih2|Whh2);
    // L1 uses af[tl*2+s] (s=0..1, Whh1). bs = role bias; w1v/wlu role-only. ----
    half8 af[8];
    f32x4 bs[2], w1v[2];
    float wlu[2];
#pragma unroll
    for (int tl = 0; tl < 2; ++tl) {
        const bool tv = (wvv + 7*tl) < 13;
        const int lr = 16*(wvv + 7*tl) + nn;
        const int ua_ = lr >> 2, ga = lr & 3;
        const bool av = tv && (ua_ < Hh);
        const int pr = av ? (ga*Hh + ua_) : 0;
        const float rs = (ga == 2) ? TL2E : L2E;
        if (isL2) {
#pragma unroll
            for (int s = 0; s < 4; ++s)
#pragma unroll
                for (int j = 0; j < 8; ++j) {
                    int k = 32*s + quad*8 + j;
                    float w = 0.f;
                    if (av) {
                        if (k < Hh)                    w = Wih2[pr*Hh + k]*rs;
                        else if (k >= 64 && k < 64+Hh) w = Whh2[pr*Hh + (k-64)]*rs;
                    }
                    af[tl*4+s][j] = (_Float16)w;
                }
        } else {
#pragma unroll
            for (int s = 0; s < 2; ++s)
#pragma unroll
                for (int j = 0; j < 8; ++j) {
                    int k = 32*s + quad*8 + j;
                    float w = (av && k < Hh) ? Whh1[pr*Hh + k]*rs : 0.f;
                    af[tl*2+s][j] = (_Float16)w;
                }
        }
        const int u = 4*(wvv + 7*tl) + quad;
        const bool uv = tv && (u < Hh);
#pragma unroll
        for (int i = 0; i < 4; ++i) {
            int pri = uv ? (i*Hh + u) : 0;
            float gs = (i == 2) ? TL2E : L2E;
            if (isL2) {
                bs[tl][i]  = uv ? (bih2[pri] + bhh2[pri])*gs : 0.f;
                w1v[tl][i] = 0.f;
            } else {
                bs[tl][i]  = uv ? (bih1[pri] + bhh1[pri])*gs : 0.f;
                w1v[tl][i] = uv ? Wih1[pri]*gs : 0.f;
            }
        }
        wlu[tl] = (isL2 && uv) ? Wl[u] : 0.f;
    }
    const float blv = blp[0];

    // ---- assigned cell for this lane: (ua, ba); role c-state lives here ----
    const int  ua  = 4*(wvv + (lo ? 0 : 7)) + quad;
    const bool uva = (ua < Hh);
    const float wlua = lo ? wlu[0] : wlu[1];
    float cst = 0.f;                    // c2 for L2 waves, c1 for L1 waves

    // ---- prologue: h1(0) by L1 waves (they own c1) ----
    if (!isL2) {
        float b1a[4], w1a[4];
#pragma unroll
        for (int i = 0; i < 4; ++i) {
            b1a[i] = lo ? bs[0][i] : bs[1][i];
            w1a[i] = lo ? w1v[0][i] : w1v[1][i];
        }
        float x0 = inp[(size_t)(b0 + ba)*Tin];
        float vi = __builtin_fmaf(w1a[0], x0, b1a[0]);
        float vf = __builtin_fmaf(w1a[1], x0, b1a[1]);
        float vg = __builtin_fmaf(w1a[2], x0, b1a[2]);
        float vo = __builtin_fmaf(w1a[3], x0, b1a[3]);
        float h1n = cell_fuse(vi, vf, vg, vo, cst);
        if (uva) Bh[0][ba*BST + ua] = f2h(h1n);
    }
    float xreg = (!isL2 && Tin > 1) ? inp[(size_t)(b0 + ba)*Tin + 1] : 0.f;
    __syncthreads();

    // ================= input-mode loop: t in [0, Tin-1) =================
    for (int t = 0; t < Tin-1; ++t) {
        const int cur = t & 1, nxt = cur ^ 1;

        // ---- B-frag reads first; L1 waves only need slabs 0,1 ----
        const uint16_t* rb = &Bh[cur][ba*BST + quad*8];
        half8 s0 = *(const half8*)(rb), s1 = *(const half8*)(rb + 32);
        half8 s2, s3;
        if (isL2) { s2 = *(const half8*)(rb + 64); s3 = *(const half8*)(rb + 96); }

        // out(t-1) write (wave 6 only; reads previous step's wsum[nxt])
        if (wv == NTP-1 && t > 0) {
            float osum = blv;
#pragma unroll
            for (int w = 0; w < NTP; ++w)
                osum += wsum[nxt][w*WS + ba] + wsum[nxt][w*WS + 8 + ba];
            if (ln < NBB) outp[(size_t)(b0 + ln)*Ttot + (t-1)] = osum;
        }
        float xn = (!isL2 && t + 2 < Tin) ? inp[(size_t)(b0 + ba)*Tin + t + 2] : 0.f;

        if (isL2) {
            // ---- L2(t): 8 MFMA, h2 cell, wsum partial ----
            f32x4 aA0 = bs[0], aB0 = {0.f,0.f,0.f,0.f};
            f32x4 aA1 = bs[1], aB1 = {0.f,0.f,0.f,0.f};
            aA0 = MFMA(af[0], s0, aA0, 0,0,0);  aB0 = MFMA(af[1], s1, aB0, 0,0,0);
            aA1 = MFMA(af[4], s0, aA1, 0,0,0);  aB1 = MFMA(af[5], s1, aB1, 0,0,0);
            aA0 = MFMA(af[2], s2, aA0, 0,0,0);  aB0 = MFMA(af[3], s3, aB0, 0,0,0);
            aA1 = MFMA(af[6], s2, aA1, 0,0,0);  aB1 = MFMA(af[7], s3, aB1, 0,0,0);
            f32x4 gt0 = aA0 + aB0, gt1 = aA1 + aB1;
            float g[4];
#pragma unroll
            for (int i = 0; i < 4; ++i) g[i] = lo ? gt0[i] : gt1[i];
            float h2v = cell_fuse(g[0], g[1], g[2], g[3], cst);
            if (uva) Bh[nxt][ba*BST + 64 + ua] = f2h(h2v);
            float part = qsum(wlua * h2v);
            if (ln < 16) wsum[cur][wvv*WS + ln] = part;
        } else {
            // ---- L1(t+1): 4 MFMA, h1 cell ----
            f32x4 bA0, bA1, bB0 = {0.f,0.f,0.f,0.f}, bB1 = {0.f,0.f,0.f,0.f};
#pragma unroll
            for (int i = 0; i < 4; ++i) {
                bA0[i] = __builtin_fmaf(w1v[0][i], xreg, bs[0][i]);
                bA1[i] = __builtin_fmaf(w1v[1][i], xreg, bs[1][i]);
            }
            bA0 = MFMA(af[0], s0, bA0, 0,0,0);  bB0 = MFMA(af[1], s1, bB0, 0,0,0);
            bA1 = MFMA(af[2], s0, bA1, 0,0,0);  bB1 = MFMA(af[3], s1, bB1, 0,0,0);
            f32x4 gt0 = bA0 + bB0, gt1 = bA1 + bB1;
            float g[4];
#pragma unroll
            for (int i = 0; i < 4; ++i) g[i] = lo ? gt0[i] : gt1[i];
            float h1v = cell_fuse(g[0], g[1], g[2], g[3], cst);
            if (uva) Bh[nxt][ba*BST + ua] = f2h(h1v);
        }

        __syncthreads();
        xreg = xn;
    }

    // ================= future loop: t in [Tin-1, Ttot) =================
    for (int t = Tin-1; t < Ttot; ++t) {
        const int cur = t & 1, nxt = cur ^ 1;

        const uint16_t* rb = &Bh[cur][ba*BST + quad*8];
        half8 s0 = *(const half8*)(rb), s1 = *(const half8*)(rb + 32);
        half8 s2, s3;
        if (isL2) { s2 = *(const half8*)(rb + 64); s3 = *(const half8*)(rb + 96); }

        if (wv == NTP-1) {      // t >= 511 > 0 always
            float osum = blv;
#pragma unroll
            for (int w = 0; w < NTP; ++w)
                osum += wsum[nxt][w*WS + ba] + wsum[nxt][w*WS + 8 + ba];
            if (ln < NBB) outp[(size_t)(b0 + ln)*Ttot + (t-1)] = osum;
        }

        if (isL2) {
            f32x4 aA0 = bs[0], aB0 = {0.f,0.f,0.f,0.f};
            f32x4 aA1 = bs[1], aB1 = {0.f,0.f,0.f,0.f};
            aA0 = MFMA(af[0], s0, aA0, 0,0,0);  aB0 = MFMA(af[1], s1, aB0, 0,0,0);
            aA1 = MFMA(af[4], s0, aA1, 0,0,0);  aB1 = MFMA(af[5], s1, aB1, 0,0,0);
            aA0 = MFMA(af[2], s2, aA0, 0,0,0);  aB0 = MFMA(af[3], s3, aB0, 0,0,0);
            aA1 = MFMA(af[6], s2, aA1, 0,0,0);  aB1 = MFMA(af[7], s3, aB1, 0,0,0);
            f32x4 gt0 = aA0 + aB0, gt1 = aA1 + aB1;
            float g[4];
#pragma unroll
            for (int i = 0; i < 4; ++i) g[i] = lo ? gt0[i] : gt1[i];
            float h2v = cell_fuse(g[0], g[1], g[2], g[3], cst);
            if (uva) Bh[nxt][ba*BST + 64 + ua] = f2h(h2v);
            float part = qsum(wlua * h2v);
            if (ln < 16) wsum[cur][wvv*WS + ln] = part;
        }
        __syncthreads();                                   // bar 1

        if (t + 1 < Ttot) {
            if (!isL2) {
                // x(t+1) = out(t) from wsum[cur], then L1(t+1)
                float osum = blv;
#pragma unroll
                for (int w = 0; w < NTP; ++w)
                    osum += wsum[cur][w*WS + ba] + wsum[cur][w*WS + 8 + ba];
                f32x4 bA0, bA1, bB0 = {0.f,0.f,0.f,0.f}, bB1 = {0.f,0.f,0.f,0.f};
#pragma unroll
                for (int i = 0; i < 4; ++i) {
                    bA0[i] = __builtin_fmaf(w1v[0][i], osum, bs[0][i]);
                    bA1[i] = __builtin_fmaf(w1v[1][i], osum, bs[1][i]);
                }
                bA0 = MFMA(af[0], s0, bA0, 0,0,0);  bB0 = MFMA(af[1], s1, bB0, 0,0,0);
                bA1 = MFMA(af[2], s0, bA1, 0,0,0);  bB1 = MFMA(af[3], s1, bB1, 0,0,0);
                f32x4 gt0 = bA0 + bB0, gt1 = bA1 + bB1;
                float g[4];
#pragma unroll
                for (int i = 0; i < 4; ++i) g[i] = lo ? gt0[i] : gt1[i];
                float h1v = cell_fuse(g[0], g[1], g[2], g[3], cst);
                if (uva) Bh[nxt][ba*BST + ua] = f2h(h1v);
            }
            __syncthreads();                               // bar 2 (future only)
        }
    }

    // final output (t = Ttot-1): wsum[(Ttot-1)&1] visible after last bar 1
    if (wv == NTP-1) {
        float osum = blv;
#pragma unroll
        for (int w = 0; w < NTP; ++w)
            osum += wsum[(Ttot-1)&1][w*WS + ba] + wsum[(Ttot-1)&1][w*WS + 8 + ba];
        if (ln < NBB) outp[(size_t)(b0 + ln)*Ttot + (Ttot-1)] = osum;
    }
}

extern "C" void kernel_launch(void* const* d_in, const int* in_sizes, int n_in,
                              void* d_out, int out_size, void* d_ws, size_t ws_size,
                              hipStream_t stream) {
    (void)in_sizes; (void)n_in; (void)out_size; (void)d_ws; (void)ws_size;
    lstm_f16s2<<<dim3(Bsz / NBB), dim3(BLK), 0, stream>>>(
        (const float*)d_in[0], (const float*)d_in[1],
        (const float*)d_in[2], (const float*)d_in[3],
        (const float*)d_in[4], (const float*)d_in[5],
        (const float*)d_in[6], (const float*)d_in[7],
        (const float*)d_in[8], (const float*)d_in[9],
        (const float*)d_in[10], (float*)d_out);
}